// Round 8
// baseline (313.422 us; speedup 1.0000x reference)
//
#include <hip/hip_runtime.h>
#include <hip/hip_bf16.h>

#define B_   4
#define N_   2048
#define IN_  256
#define OUT_ 256
#define H_   4
#define HD_  64
#define LN_EPS 1e-5f

typedef __bf16 bf16x8 __attribute__((ext_vector_type(8)));
typedef float  f32x4  __attribute__((ext_vector_type(4)));
typedef unsigned short u16x8 __attribute__((ext_vector_type(8)));
typedef unsigned int   u32x2 __attribute__((ext_vector_type(2)));
typedef unsigned int   u32x4 __attribute__((ext_vector_type(4)));

__device__ __forceinline__ unsigned short f2bf(float x) {
    unsigned int u = __float_as_uint(x);
    return (unsigned short)((u + 0x7FFFu + ((u >> 16) & 1u)) >> 16);
}
__device__ __forceinline__ float bf2f(unsigned short u) {
    return __uint_as_float((unsigned int)u << 16);
}
__device__ __forceinline__ unsigned int cvtpk(float lo, float hi) {
    unsigned int r;
    asm("v_cvt_pk_bf16_f32 %0, %1, %2" : "=v"(r) : "v"(lo), "v"(hi));
    return r;
}

// ---------------------------------------------------------------------------
// conv: nf -> bf16 (nfb), W_{lin,q,k} -> bf16 transposed (Wt[z][n][k])
// ---------------------------------------------------------------------------
__global__ __launch_bounds__(256) void conv_kernel(
    const float* __restrict__ nf, const float* __restrict__ Wl,
    const float* __restrict__ Wq, const float* __restrict__ Wk,
    unsigned short* __restrict__ nfb, unsigned short* __restrict__ Wt)
{
    const int bid = blockIdx.x, tid = threadIdx.x;
    if (bid < 1024) {
        size_t i = ((size_t)bid * 256 + tid) * 8;
        u16x8 o;
        #pragma unroll
        for (int j = 0; j < 8; j++) o[j] = f2bf(nf[i + j]);
        *(u16x8*)&nfb[i] = o;
    } else {
        int t = (bid - 1024) * 256 + tid;   // 0..196607
        int z = t >> 16;
        int l = t & 65535;
        int k = l & 255, n = l >> 8;
        const float* W = (z == 0) ? Wl : (z == 1 ? Wq : Wk);
        Wt[(size_t)z * 65536 + n * 256 + k] = f2bf(W[k * 256 + n]);
    }
}

// ---------------------------------------------------------------------------
// gemm3: X/q/k = lrelu(nfb @ W + bias), barrier-free fragment GEMM
// ---------------------------------------------------------------------------
__global__ __launch_bounds__(256) void gemm3_kernel(
    const unsigned short* __restrict__ nfb, const unsigned short* __restrict__ Wt3,
    const float* __restrict__ bl,
    unsigned short* __restrict__ qb, unsigned short* __restrict__ kb,
    unsigned short* __restrict__ Xt)
{
    const int z  = blockIdx.z;
    const int m0 = blockIdx.x * 64, n0 = blockIdx.y * 64;
    const int tid = threadIdx.x, wave = tid >> 6, lane = tid & 63;
    const int lq = lane >> 4, lr = lane & 15;
    const unsigned short* Wt = Wt3 + (size_t)z * 65536;

    f32x4 acc[4] = {};
    #pragma unroll 4
    for (int k0 = 0; k0 < IN_; k0 += 32) {
        bf16x8 af = *(const bf16x8*)&nfb[(size_t)(m0 + wave * 16 + lr) * IN_ + k0 + lq * 8];
        #pragma unroll
        for (int f = 0; f < 4; f++) {
            bf16x8 bfr = *(const bf16x8*)&Wt[(size_t)(n0 + f * 16 + lr) * IN_ + k0 + lq * 8];
            acc[f] = __builtin_amdgcn_mfma_f32_16x16x32_bf16(af, bfr, acc[f], 0, 0, 0);
        }
    }

    #pragma unroll
    for (int f = 0; f < 4; f++) {
        int c = n0 + f * 16 + lr;
        float bias = (z == 0) ? bl[c] : 0.0f;
        #pragma unroll
        for (int r = 0; r < 4; r++) {
            int m = m0 + wave * 16 + lq * 4 + r;
            float v = acc[f][r] + bias;
            v = (v >= 0.f) ? v : 0.01f * v;
            unsigned short bv = f2bf(v);
            if (z == 0) {
                int n = m & (N_ - 1);
                int h = c >> 6, d = c & 63;
                Xt[(((size_t)(m >> 11) * H_ + h) * HD_ + d) * N_ + n] = bv;
            } else {
                unsigned short* dst = (z == 1) ? qb : kb;
                dst[(size_t)m * OUT_ + c] = bv;
            }
        }
    }
}

// ---------------------------------------------------------------------------
// att-v5: W = adj*sigmoid(q.k/8) (bf16) + atomic row sums into deg.
// 128x128 tile, 4 waves 2x2. adj staged bf16 in LDS (coalesced), w written
// in-place, coalesced u16x8 store phase.
// ---------------------------------------------------------------------------
__global__ __launch_bounds__(256) void att_kernel(
    const float* __restrict__ adj,
    const unsigned short* __restrict__ qb,
    const unsigned short* __restrict__ kb,
    unsigned short* __restrict__ W,      // chunk: [s_local][N][N]
    float* __restrict__ deg,             // full [B*H][N], pre-zeroed
    int b_base, int SH)
{
    const int s  = blockIdx.z;
    const int bg = b_base + (s >> 2);
    const int hg = s & 3;
    const int x0 = blockIdx.x * 128, y0 = blockIdx.y * 128;
    const int tid = threadIdx.x, wave = tid >> 6, lane = tid & 63;
    const int lq = lane >> 4, lr = lane & 15;
    const int wq = wave >> 1, wn = wave & 1;
    const int wx0 = wq * 64, wy0 = wn * 64;           // local offsets
    const float sc = -0.125f * 1.44269504088896f;

    __shared__ unsigned short ads[128][136];

    // --- stage adj 128x128 f32 -> bf16 LDS (coalesced f32x4 loads) ---
    {
        const int row0 = tid >> 5;                    // 0..7
        const int col  = (tid & 31) * 4;              // 0..124
        const float* ap = adj + ((size_t)bg * N_ + x0 + row0) * N_ + y0 + col;
        #pragma unroll 4
        for (int i = 0; i < 16; i++) {
            f32x4 v = *(const f32x4*)(ap + (size_t)i * 8 * N_);
            u32x2 p = { cvtpk(v[0], v[1]), cvtpk(v[2], v[3]) };
            *(u32x2*)&ads[row0 + i * 8][col] = p;
        }
    }

    // --- QK^T MFMA (global frag loads, L2-resident q/k) ---
    const unsigned short* qrow = qb + (size_t)(bg * N_ + x0 + wx0) * OUT_ + hg * HD_;
    const unsigned short* krow = kb + (size_t)(bg * N_ + y0 + wy0) * OUT_ + hg * HD_;
    f32x4 acc[4][4] = {};
    #pragma unroll
    for (int ks = 0; ks < 2; ks++) {
        bf16x8 af[4];
        #pragma unroll
        for (int mf = 0; mf < 4; mf++)
            af[mf] = *(const bf16x8*)&qrow[(size_t)(mf * 16 + lr) * OUT_ + ks * 32 + lq * 8];
        #pragma unroll
        for (int nf = 0; nf < 4; nf++) {
            bf16x8 bfr = *(const bf16x8*)&krow[(size_t)(nf * 16 + lr) * OUT_ + ks * 32 + lq * 8];
            #pragma unroll
            for (int mf = 0; mf < 4; mf++)
                acc[mf][nf] = __builtin_amdgcn_mfma_f32_16x16x32_bf16(af[mf], bfr, acc[mf][nf], 0, 0, 0);
        }
    }
    __syncthreads();    // adj staged

    // --- epilogue: w = adj*sigmoid in-place in LDS, + atomic row sums ---
    float* degrow = deg + ((size_t)bg * H_ + hg) * N_ + x0;
    #pragma unroll
    for (int mf = 0; mf < 4; mf++) {
        #pragma unroll
        for (int r = 0; r < 4; r++) {
            const int xl = wx0 + mf * 16 + lq * 4 + r;
            float sum = 0.f;
            #pragma unroll
            for (int nf = 0; nf < 4; nf++) {
                const int yl = wy0 + nf * 16 + lr;
                float a = bf2f(ads[xl][yl]);
                float att = __builtin_amdgcn_rcpf(1.f + exp2f(acc[mf][nf][r] * sc));
                float wv = a * att;
                ads[xl][yl] = (unsigned short)cvtpk(wv, wv);
                sum += wv;
            }
            sum += __shfl_xor(sum, 1); sum += __shfl_xor(sum, 2);
            sum += __shfl_xor(sum, 4); sum += __shfl_xor(sum, 8);
            if (lr == 0)
                atomicAdd(&degrow[xl], sum);
        }
    }
    __syncthreads();    // all w written

    // --- coalesced store: 16B/lane, 256B segments ---
    unsigned short* Wp = W + (size_t)s * N_ * N_;
    const int col = (tid & 15) * 8;
    const int r0  = tid >> 4;                         // 0..15
    #pragma unroll
    for (int i = 0; i < 8; i++) {
        int row = i * 16 + r0;
        u16x8 v = *(const u16x8*)&ads[row][col];
        *(u16x8*)&Wp[(size_t)(x0 + row) * N_ + y0 + col] = v;
    }
}

// ---------------------------------------------------------------------------
// scale: Xs = Xt * rsqrt(deg_y) (bf16); pointers pre-offset to chunk
// ---------------------------------------------------------------------------
__global__ __launch_bounds__(256) void scale_kernel(
    const unsigned short* __restrict__ Xt, const float* __restrict__ deg,
    unsigned short* __restrict__ Xs)
{
    int t = blockIdx.x * 256 + threadIdx.x;
    size_t idx = (size_t)t * 8;
    int s = t >> 14;                         // HD*N/8 = 16384
    int y = (int)(idx & (N_ - 1));
    f32x4 g0 = *(const f32x4*)&deg[(size_t)s * N_ + y];
    f32x4 g1 = *(const f32x4*)&deg[(size_t)s * N_ + y + 4];
    float dv[8];
    #pragma unroll
    for (int j = 0; j < 4; j++) {
        dv[j]     = (g0[j] > 0.f) ? rsqrtf(g0[j]) : 0.f;
        dv[4 + j] = (g1[j] > 0.f) ? rsqrtf(g1[j]) : 0.f;
    }
    u16x8 x = *(const u16x8*)&Xt[idx];
    u32x4 o;
    o[0] = cvtpk(bf2f(x[0]) * dv[0], bf2f(x[1]) * dv[1]);
    o[1] = cvtpk(bf2f(x[2]) * dv[2], bf2f(x[3]) * dv[3]);
    o[2] = cvtpk(bf2f(x[4]) * dv[4], bf2f(x[5]) * dv[5]);
    o[3] = cvtpk(bf2f(x[6]) * dv[6], bf2f(x[7]) * dv[7]);
    *(u32x4*)&Xs[idx] = o;
}

// ---------------------------------------------------------------------------
// yout-v3: Yraw = rsqrt(deg_x) * (W @ Xs), LDS-staged double-buffered GEMM.
// ---------------------------------------------------------------------------
__global__ __launch_bounds__(512) void yout_kernel(
    const unsigned short* __restrict__ W,    // chunk base [s][N][N]
    const unsigned short* __restrict__ Xs,   // chunk base [s][64][N]
    const float* __restrict__ deg,           // full [B*H][N]
    float* __restrict__ Yraw,                // full [B][N][256]
    int b_base)
{
    const int s  = blockIdx.y;               // local slice
    const int bg = b_base + (s >> 2);
    const int hg = s & 3;
    const int x0 = blockIdx.x * 32;
    const int tid = threadIdx.x;
    const int wave = tid >> 6, lane = tid & 63;
    const int xw = wave >> 2, dq = wave & 3;
    const int lq = lane >> 4, lr = lane & 15;

    __shared__ unsigned short As[2][32 * 256];

    const int srow = tid >> 4, kslot = tid & 15;
    const int swz  = (srow & 7) << 4;
    const unsigned short* Wrow =
        W + (size_t)s * N_ * N_ + (size_t)(x0 + srow) * N_ + kslot * 16;

    const unsigned short* Xp = Xs + ((size_t)s * HD_ + dq * 16 + lr) * N_;

    const int arow = xw * 16 + lr;
    const int arsw = (arow & 7) << 4;

    f32x4 Y = {};

    {
        u16x8 r0 = *(const u16x8*)&Wrow[0];
        u16x8 r1 = *(const u16x8*)&Wrow[8];
        char* base = (char*)&As[0][0] + srow * 512;
        *(u16x8*)(base + ((kslot * 32) ^ swz))      = r0;
        *(u16x8*)(base + ((kslot * 32 + 16) ^ swz)) = r1;
    }
    __syncthreads();

    int cur = 0;
    for (int kt = 0; kt < 8; kt++) {
        u16x8 n0, n1;
        if (kt < 7) {
            n0 = *(const u16x8*)&Wrow[(kt + 1) * 256];
            n1 = *(const u16x8*)&Wrow[(kt + 1) * 256 + 8];
        }
        const char* abase = (const char*)&As[cur][0] + arow * 512;
        #pragma unroll
        for (int half = 0; half < 2; half++) {
            bf16x8 xf[4];
            #pragma unroll
            for (int u = 0; u < 4; u++)
                xf[u] = *(const bf16x8*)&Xp[kt * 256 + (half * 4 + u) * 32 + lq * 8];
            #pragma unroll
            for (int u = 0; u < 4; u++) {
                const int kb = ((half * 4 + u) * 32 + lq * 8) * 2;
                bf16x8 af = *(const bf16x8*)(abase + (kb ^ arsw));
                Y = __builtin_amdgcn_mfma_f32_16x16x32_bf16(af, xf[u], Y, 0, 0, 0);
            }
        }
        if (kt < 7) {
            char* base = (char*)&As[cur ^ 1][0] + srow * 512;
            *(u16x8*)(base + ((kslot * 32) ^ swz))      = n0;
            *(u16x8*)(base + ((kslot * 32 + 16) ^ swz)) = n1;
        }
        __syncthreads();
        cur ^= 1;
    }

    #pragma unroll
    for (int r = 0; r < 4; r++) {
        int x = x0 + xw * 16 + lq * 4 + r;
        float g = deg[((size_t)bg * H_ + hg) * N_ + x];
        float dx = (g > 0.f) ? rsqrtf(g) : 0.f;
        Yraw[((size_t)(bg * N_ + x)) * OUT_ + hg * HD_ + dq * 16 + lr] = Y[r] * dx;
    }
}

// ---------------------------------------------------------------------------
// ln: LayerNorm over 256 cols per row
// ---------------------------------------------------------------------------
__global__ __launch_bounds__(256) void ln_kernel(
    const float* __restrict__ Yraw,
    const float* __restrict__ lng, const float* __restrict__ lnb,
    float* __restrict__ out)
{
    const int row = blockIdx.x;
    const int c = threadIdx.x;
    const size_t base = (size_t)row * OUT_ + c;
    float v = Yraw[base];

    float s1 = v, s2 = v * v;
    #pragma unroll
    for (int d = 1; d < 64; d <<= 1) { s1 += __shfl_xor(s1, d); s2 += __shfl_xor(s2, d); }
    __shared__ float red[2][4];
    if ((c & 63) == 0) { red[0][c >> 6] = s1; red[1][c >> 6] = s2; }
    __syncthreads();
    float t1 = red[0][0] + red[0][1] + red[0][2] + red[0][3];
    float t2 = red[1][0] + red[1][1] + red[1][2] + red[1][3];
    float mu  = t1 * (1.f / 256.f);
    float var = t2 * (1.f / 256.f) - mu * mu;
    float rs  = rsqrtf(var + LN_EPS);
    out[base] = (v - mu) * rs * lng[c] + lnb[c];
}

extern "C" void kernel_launch(void* const* d_in, const int* in_sizes, int n_in,
                              void* d_out, int out_size, void* d_ws, size_t ws_size,
                              hipStream_t stream) {
    const float* nf  = (const float*)d_in[0];
    const float* adj = (const float*)d_in[1];
    const float* Wl  = (const float*)d_in[2];
    const float* bl  = (const float*)d_in[3];
    const float* Wq  = (const float*)d_in[4];
    const float* Wk  = (const float*)d_in[5];
    const float* lng = (const float*)d_in[6];
    const float* lnb = (const float*)d_in[7];
    float* out = (float*)d_out;

    char* w = (char*)d_ws;
    unsigned short* nfb = (unsigned short*)w;  w += (size_t)B_ * N_ * IN_ * 2;
    unsigned short* Wt  = (unsigned short*)w;  w += (size_t)3 * IN_ * OUT_ * 2;
    unsigned short* qb  = (unsigned short*)w;  w += (size_t)B_ * N_ * OUT_ * 2;
    unsigned short* kb  = (unsigned short*)w;  w += (size_t)B_ * N_ * OUT_ * 2;
    unsigned short* Xt  = (unsigned short*)w;  w += (size_t)B_ * N_ * OUT_ * 2;
    unsigned short* Xs  = (unsigned short*)w;  w += (size_t)B_ * N_ * OUT_ * 2;
    float* deg  = (float*)w;                   w += (size_t)B_ * H_ * N_ * 4;
    float* Yraw = (float*)w;                   w += (size_t)B_ * N_ * OUT_ * 4;
    size_t fixed = (size_t)(w - (char*)d_ws);

    // nb batches per chunk: 4 if ws fits the full 134MB W buffer, else 1
    size_t need4 = fixed + (size_t)16 * N_ * N_ * 2;
    int nb = (ws_size >= need4) ? 4 : 1;
    int SH = nb * H_;
    unsigned short* Wbuf = (unsigned short*)w;

    hipMemsetAsync(deg, 0, (size_t)B_ * H_ * N_ * 4, stream);
    conv_kernel <<<1792, 256, 0, stream>>>(nf, Wl, Wq, Wk, nfb, Wt);
    gemm3_kernel<<<dim3(128, 4, 3), 256, 0, stream>>>(nfb, Wt, bl, qb, kb, Xt);

    for (int b0 = 0; b0 < B_; b0 += nb) {
        size_t xoff = (size_t)b0 * H_ * HD_ * N_;
        att_kernel  <<<dim3(16, 16, SH), 256, 0, stream>>>(adj, qb, kb, Wbuf, deg, b0, SH);
        scale_kernel<<<SH * HD_ * N_ / 8 / 256, 256, 0, stream>>>(Xt + xoff, deg + (size_t)b0 * H_ * N_, Xs + xoff);
        yout_kernel <<<dim3(N_ / 32, SH), 512, 0, stream>>>(Wbuf, Xs + xoff, deg, Yraw, b0);
    }
    ln_kernel<<<B_ * N_, 256, 0, stream>>>(Yraw, lng, lnb, out);
}